// Round 1
// baseline (579082.275 us; speedup 1.0000x reference)
//
#include <hip/hip_runtime.h>
#include <hip/hip_cooperative_groups.h>
#include <math.h>

namespace cg = cooperative_groups;

// Problem constants
#define Bz 512
#define Sz 128
#define Dz 128
#define Hz 1024
#define Lz 128
#define NSUB 4

// Launch / tiling constants
#define GRID 256
#define BLOCK 256
#define TM 32
#define TN 64
#define BKK 32
#define LDAS (TM + 2)   // As row stride (k-major), keeps float2 reads 8B-aligned
#define LDBS (TN + 4)   // Bs row stride (k-major), keeps float4 reads 16B-aligned
#define SMEM_FLOATS (BKK * LDAS + BKK * LDBS)

enum { EPI_NONE = 0, EPI_Y = 1, EPI_H = 2 };

// DPA_C[i] = dopri5 tableau row i+1 (coefficients for the input of stage i+1).
// Row 5 == the 5th-order b-weights (FSAL): h_next = y_6. Stage 7 f-eval is dead.
__constant__ float DPA_C[6][6] = {
  {0.2f, 0.f, 0.f, 0.f, 0.f, 0.f},
  {0.075f, 0.225f, 0.f, 0.f, 0.f, 0.f},
  {44.f/45.f, -56.f/15.f, 32.f/9.f, 0.f, 0.f, 0.f},
  {19372.f/6561.f, -25360.f/2187.f, 64448.f/6561.f, -212.f/729.f, 0.f, 0.f},
  {9017.f/3168.f, -355.f/33.f, 46732.f/5247.f, 49.f/176.f, -5103.f/18656.f, 0.f},
  {35.f/384.f, 0.f, 500.f/1113.f, 125.f/192.f, -2187.f/6784.f, 11.f/84.f},
};

struct KArgs {
  const float *x, *t, *w_ih, *w_hh, *b_ih, *b_hh;
  const float *w0, *b0, *w1, *b1, *w2, *b2, *mu_w, *mu_b, *lv_w, *lv_b;
  float *out;
  float *hA, *hB, *y, *t1, *t2, *k0, *k1, *k2, *k3, *k4, *gi, *gh;
};

// One TM x TN tile of C[M=512,N] = A[512,K] @ W[N,K]^T + bias, optional tanh,
// optional fused dopri5 epilogue (EPI_Y: write y_{stage+1}; EPI_H: write h_next).
__device__ __forceinline__ void gemm_tile(
    const float* __restrict__ A, int lda,
    const float* __restrict__ W, int K,
    const float* __restrict__ bias,
    float* __restrict__ C, int ldc,
    int row0, int col0,
    int act, int epi,
    const float* __restrict__ hb, float* __restrict__ ydst,
    const float* __restrict__ k0b, const float* __restrict__ k1b,
    const float* __restrict__ k2b, const float* __restrict__ k3b,
    const float* __restrict__ k4b,
    int stage, float hs,
    float* __restrict__ As, float* __restrict__ Bs)
{
  const int tid = threadIdx.x;
  const int lm  = tid >> 3;          // 0..31: row (A) / col (W) within tile for loads
  const int lk4 = (tid & 7) << 2;    // 0,4,...,28: k offset for loads
  const int r   = tid >> 4;          // 0..15: row group (2 rows)
  const int cg4 = (tid & 15) << 2;   // col group (4 cols)

  float acc[2][4] = {{0.f,0.f,0.f,0.f},{0.f,0.f,0.f,0.f}};

  const float* Aptr = A + (size_t)(row0 + lm) * lda + lk4;
  const float* W0   = W + (size_t)(col0 + lm) * K + lk4;
  const float* W1   = W + (size_t)(col0 + lm + 32) * K + lk4;

  // prefetch first chunk
  float4 av  = *(const float4*)(Aptr);
  float4 bv0 = *(const float4*)(W0);
  float4 bv1 = *(const float4*)(W1);

  for (int kk = 0; kk < K; kk += BKK) {
    __syncthreads();   // previous chunk's (or previous tile's) LDS reads done
    As[(lk4+0)*LDAS + lm] = av.x;
    As[(lk4+1)*LDAS + lm] = av.y;
    As[(lk4+2)*LDAS + lm] = av.z;
    As[(lk4+3)*LDAS + lm] = av.w;
    Bs[(lk4+0)*LDBS + lm] = bv0.x;
    Bs[(lk4+1)*LDBS + lm] = bv0.y;
    Bs[(lk4+2)*LDBS + lm] = bv0.z;
    Bs[(lk4+3)*LDBS + lm] = bv0.w;
    Bs[(lk4+0)*LDBS + lm + 32] = bv1.x;
    Bs[(lk4+1)*LDBS + lm + 32] = bv1.y;
    Bs[(lk4+2)*LDBS + lm + 32] = bv1.z;
    Bs[(lk4+3)*LDBS + lm + 32] = bv1.w;
    __syncthreads();
    // prefetch next chunk while computing this one (hides L2 latency)
    if (kk + BKK < K) {
      av  = *(const float4*)(Aptr + kk + BKK);
      bv0 = *(const float4*)(W0 + kk + BKK);
      bv1 = *(const float4*)(W1 + kk + BKK);
    }
#pragma unroll
    for (int k = 0; k < BKK; ++k) {
      const float2 a2 = *(const float2*)&As[k*LDAS + (r << 1)];
      const float4 b4 = *(const float4*)&Bs[k*LDBS + cg4];
      acc[0][0] = fmaf(a2.x, b4.x, acc[0][0]);
      acc[0][1] = fmaf(a2.x, b4.y, acc[0][1]);
      acc[0][2] = fmaf(a2.x, b4.z, acc[0][2]);
      acc[0][3] = fmaf(a2.x, b4.w, acc[0][3]);
      acc[1][0] = fmaf(a2.y, b4.x, acc[1][0]);
      acc[1][1] = fmaf(a2.y, b4.y, acc[1][1]);
      acc[1][2] = fmaf(a2.y, b4.z, acc[1][2]);
      acc[1][3] = fmaf(a2.y, b4.w, acc[1][3]);
    }
  }

  const int row = row0 + (r << 1);
  const int col = col0 + cg4;
  const float4 bb = *(const float4*)&bias[col];
#pragma unroll
  for (int i = 0; i < 2; ++i) {
    float4 v;
    v.x = acc[i][0] + bb.x;
    v.y = acc[i][1] + bb.y;
    v.z = acc[i][2] + bb.z;
    v.w = acc[i][3] + bb.w;
    if (act) {
      v.x = tanhf(v.x); v.y = tanhf(v.y); v.z = tanhf(v.z); v.w = tanhf(v.w);
    }
    const size_t off = (size_t)(row + i) * ldc + col;
    if (epi == EPI_NONE) {
      *(float4*)&C[off] = v;
    } else {
      if (C) *(float4*)&C[off] = v;           // store k_stage (not needed for stage 5)
      float4 yv = *(const float4*)&hb[off];   // start from h
      const int nk = stage + 1;
      for (int j = 0; j < nk - 1; ++j) {
        const float cj = DPA_C[stage][j];
        if (cj != 0.f) {
          const float* kb = (j == 0) ? k0b : (j == 1) ? k1b : (j == 2) ? k2b
                           : (j == 3) ? k3b : k4b;
          const float hc = hs * cj;
          const float4 kv = *(const float4*)&kb[off];
          yv.x = fmaf(hc, kv.x, yv.x);
          yv.y = fmaf(hc, kv.y, yv.y);
          yv.z = fmaf(hc, kv.z, yv.z);
          yv.w = fmaf(hc, kv.w, yv.w);
        }
      }
      const float hc = hs * DPA_C[stage][nk - 1];   // coefficient of the local k
      yv.x = fmaf(hc, v.x, yv.x);
      yv.y = fmaf(hc, v.y, yv.y);
      yv.z = fmaf(hc, v.z, yv.z);
      yv.w = fmaf(hc, v.w, yv.w);
      *(float4*)&ydst[off] = yv;
    }
  }
}

__device__ __forceinline__ void gemm_phase(
    const float* __restrict__ A, int lda,
    const float* __restrict__ W, int K,
    const float* __restrict__ bias,
    float* __restrict__ C, int N, int ldc,
    int act, int epi,
    const float* __restrict__ hb, float* __restrict__ ydst,
    const float* __restrict__ k0b, const float* __restrict__ k1b,
    const float* __restrict__ k2b, const float* __restrict__ k3b,
    const float* __restrict__ k4b,
    int stage, float hs,
    float* __restrict__ As, float* __restrict__ Bs)
{
  const int tilesN = N / TN;
  const int tiles = (Bz / TM) * tilesN;
  for (int t = blockIdx.x; t < tiles; t += gridDim.x) {
    const int tm = t / tilesN;
    const int tn = t % tilesN;
    gemm_tile(A, lda, W, K, bias, C, ldc, tm * TM, tn * TN, act, epi,
              hb, ydst, k0b, k1b, k2b, k3b, k4b, stage, hs, As, Bs);
  }
}

__global__ __launch_bounds__(BLOCK) void ode_gru_kernel(KArgs a) {
  cg::grid_group grid = cg::this_grid();
  __shared__ float smem[SMEM_FLOATS];
  float* As = smem;
  float* Bs = smem + BKK * LDAS;

  float* h  = a.hA;
  float* hn = a.hB;

  // h = 0 (ws is poisoned 0xAA by the harness)
  {
    const int gstride = GRID * BLOCK;
    for (int i = blockIdx.x * BLOCK + threadIdx.x; i < Bz * Hz; i += gstride)
      h[i] = 0.f;
  }
  grid.sync();

  for (int s = 0; s < Sz; ++s) {
    if (s > 0) {
      const float dt = a.t[s] - a.t[s - 1];
      const float hs = dt * (1.0f / NSUB);
      for (int sub = 0; sub < NSUB; ++sub) {
        const float* yin = h;
        for (int st = 0; st < 6; ++st) {
          // MLP layer 1 (tanh)
          gemm_phase(yin, Hz, a.w0, Hz, a.b0, a.t1, Hz, Hz, 1, EPI_NONE,
                     nullptr, nullptr, a.k0, a.k1, a.k2, a.k3, a.k4, 0, 0.f, As, Bs);
          grid.sync();
          // MLP layer 2 (tanh)
          gemm_phase(a.t1, Hz, a.w1, Hz, a.b1, a.t2, Hz, Hz, 1, EPI_NONE,
                     nullptr, nullptr, a.k0, a.k1, a.k2, a.k3, a.k4, 0, 0.f, As, Bs);
          grid.sync();
          // MLP layer 3 (linear) -> k_st, fused dopri5 combine in epilogue
          float* kdst;
          float* yd;
          int epi;
          if (st < 5) {
            kdst = (st == 0) ? a.k0 : (st == 1) ? a.k1 : (st == 2) ? a.k2
                 : (st == 3) ? a.k3 : a.k4;
            yd = a.y;
            epi = EPI_Y;
          } else {
            kdst = nullptr;   // k5 only needed locally (FSAL: h_next = y_6)
            yd = hn;
            epi = EPI_H;
          }
          gemm_phase(a.t2, Hz, a.w2, Hz, a.b2, kdst, Hz, Hz, 0, epi,
                     h, yd, a.k0, a.k1, a.k2, a.k3, a.k4, st, hs, As, Bs);
          grid.sync();
          yin = a.y;
        }
        { float* tmp = h; h = hn; hn = tmp; }
      }
    }

    // GRU: gi = x_s @ w_ih^T + b_ih ; gh = h @ w_hh^T + b_hh (independent, one sync)
    gemm_phase(a.x + (size_t)s * Dz, Sz * Dz, a.w_ih, Dz, a.b_ih, a.gi, 3 * Hz, 3 * Hz,
               0, EPI_NONE, nullptr, nullptr, a.k0, a.k1, a.k2, a.k3, a.k4, 0, 0.f, As, Bs);
    gemm_phase(h, Hz, a.w_hh, Hz, a.b_hh, a.gh, 3 * Hz, 3 * Hz,
               0, EPI_NONE, nullptr, nullptr, a.k0, a.k1, a.k2, a.k3, a.k4, 0, 0.f, As, Bs);
    grid.sync();

    // GRU pointwise
    {
      const int gstride = GRID * BLOCK;
      for (int i = blockIdx.x * BLOCK + threadIdx.x; i < Bz * Hz; i += gstride) {
        const int b = i >> 10;       // / Hz
        const int j = i & (Hz - 1);  // % Hz
        const size_t g = (size_t)b * 3 * Hz + j;
        const float ir  = a.gi[g];
        const float iz  = a.gi[g + Hz];
        const float inn = a.gi[g + 2 * Hz];
        const float hr  = a.gh[g];
        const float hzv = a.gh[g + Hz];
        const float hnn = a.gh[g + 2 * Hz];
        const float rr = 1.f / (1.f + expf(-(ir + hr)));
        const float zz = 1.f / (1.f + expf(-(iz + hzv)));
        const float nnv = tanhf(inn + rr * hnn);
        hn[i] = (1.f - zz) * nnv + zz * h[i];
      }
    }
    grid.sync();
    { float* tmp = h; h = hn; hn = tmp; }
  }

  // Final projections: mu then logvar, concatenated in d_out
  gemm_phase(h, Hz, a.mu_w, Hz, a.mu_b, a.out, Lz, Lz, 0, EPI_NONE,
             nullptr, nullptr, a.k0, a.k1, a.k2, a.k3, a.k4, 0, 0.f, As, Bs);
  gemm_phase(h, Hz, a.lv_w, Hz, a.lv_b, a.out + (size_t)Bz * Lz, Lz, Lz, 0, EPI_NONE,
             nullptr, nullptr, a.k0, a.k1, a.k2, a.k3, a.k4, 0, 0.f, As, Bs);
}

extern "C" void kernel_launch(void* const* d_in, const int* in_sizes, int n_in,
                              void* d_out, int out_size, void* d_ws, size_t ws_size,
                              hipStream_t stream) {
  KArgs a;
  a.x    = (const float*)d_in[0];
  a.t    = (const float*)d_in[1];
  a.w_ih = (const float*)d_in[2];
  a.w_hh = (const float*)d_in[3];
  a.b_ih = (const float*)d_in[4];
  a.b_hh = (const float*)d_in[5];
  a.w0   = (const float*)d_in[6];
  a.b0   = (const float*)d_in[7];
  a.w1   = (const float*)d_in[8];
  a.b1   = (const float*)d_in[9];
  a.w2   = (const float*)d_in[10];
  a.b2   = (const float*)d_in[11];
  a.mu_w = (const float*)d_in[12];
  a.mu_b = (const float*)d_in[13];
  a.lv_w = (const float*)d_in[14];
  a.lv_b = (const float*)d_in[15];
  a.out  = (float*)d_out;

  float* ws = (float*)d_ws;
  const size_t BH = (size_t)Bz * Hz;   // 524288 floats
  a.hA = ws + 0 * BH;
  a.hB = ws + 1 * BH;
  a.y  = ws + 2 * BH;
  a.t1 = ws + 3 * BH;
  a.t2 = ws + 4 * BH;
  a.k0 = ws + 5 * BH;
  a.k1 = ws + 6 * BH;
  a.k2 = ws + 7 * BH;
  a.k3 = ws + 8 * BH;
  a.k4 = ws + 9 * BH;
  a.gi = ws + 10 * BH;           // B x 3H
  a.gh = ws + 13 * BH;           // B x 3H; total 16*BH floats = 32 MiB
  (void)ws_size; (void)in_sizes; (void)n_in; (void)out_size;

  KArgs args_val = a;
  void* params[] = { &args_val };
  hipLaunchCooperativeKernel((void*)ode_gru_kernel, dim3(GRID), dim3(BLOCK),
                             params, 0, stream);
}

// Round 3
// 434558.154 us; speedup vs baseline: 1.3326x; 1.3326x over previous
//
#include <hip/hip_runtime.h>
#include <hip/hip_cooperative_groups.h>
#include <math.h>

namespace cg = cooperative_groups;

// Problem constants
#define Bz 512
#define Sz 128
#define Dz 128
#define Hz 1024
#define Lz 128
#define NSUB 4

#define GRID 256
#define BLOCK 512
#define TM 32
#define TN 64

typedef _Float16 half8 __attribute__((ext_vector_type(8)));
typedef _Float16 half4v __attribute__((ext_vector_type(4)));
typedef float floatx4 __attribute__((ext_vector_type(4)));

#define MFMA16(a, b, c) __builtin_amdgcn_mfma_f32_16x16x32_f16(a, b, c, 0, 0, 0)

// LDS layout (in halfs). Rows padded to 40 halfs (80 B) -> <=2-way bank conflicts.
#define AHI 0
#define ALO 1280
#define BHI 2560
#define BLO 5120
#define CHUNK_HALFS 7680   // 15360 B per chunk buffer; x2 = 30720 B

enum { EPI_NONE = 0, EPI_Y = 1, EPI_H = 2 };

// dopri5 tableau row i+1 (input coeffs of stage i+1). Row 5 == 5th-order b
// weights (FSAL): h_next = y_6; stage-7 f-eval is dead and skipped.
__constant__ float DPA_C[6][6] = {
  {0.2f, 0.f, 0.f, 0.f, 0.f, 0.f},
  {0.075f, 0.225f, 0.f, 0.f, 0.f, 0.f},
  {44.f/45.f, -56.f/15.f, 32.f/9.f, 0.f, 0.f, 0.f},
  {19372.f/6561.f, -25360.f/2187.f, 64448.f/6561.f, -212.f/729.f, 0.f, 0.f},
  {9017.f/3168.f, -355.f/33.f, 46732.f/5247.f, 49.f/176.f, -5103.f/18656.f, 0.f},
  {35.f/384.f, 0.f, 500.f/1113.f, 125.f/192.f, -2187.f/6784.f, 11.f/84.f},
};

struct KArgs {
  const float *x, *t, *w_ih, *w_hh, *b_ih, *b_hh;
  const float *w0, *b0, *w1, *b1, *w2, *b2, *mu_w, *mu_b, *lv_w, *lv_b;
  float* out;
  float *hA, *hB, *y, *t1, *t2, *k0, *k1, *k2, *k3, *k4, *gi, *gh;
  unsigned *slots, *root;
};

// Slot barrier: no atomic-RMW contention. Block b release-stores epoch to its
// own slot; block 0's threads poll all slots, then release the root epoch.
__device__ __forceinline__ void gbar(unsigned* slots, unsigned* root, unsigned e) {
  __syncthreads();
  if (blockIdx.x == 0) {
    const int t = threadIdx.x;
    if (t > 0 && t < GRID) {
      while (__hip_atomic_load(&slots[t], __ATOMIC_ACQUIRE, __HIP_MEMORY_SCOPE_AGENT) < e)
        __builtin_amdgcn_s_sleep(2);
    }
    __syncthreads();
    if (t == 0)
      __hip_atomic_store(root, e, __ATOMIC_RELEASE, __HIP_MEMORY_SCOPE_AGENT);
  } else {
    if (threadIdx.x == 0) {
      __hip_atomic_store(&slots[blockIdx.x], e, __ATOMIC_RELEASE, __HIP_MEMORY_SCOPE_AGENT);
      while (__hip_atomic_load(root, __ATOMIC_ACQUIRE, __HIP_MEMORY_SCOPE_AGENT) < e)
        __builtin_amdgcn_s_sleep(2);
    }
  }
  __syncthreads();
}

__device__ __forceinline__ void split4(float4 f, half4v& h, half4v& l) {
  h.x = (_Float16)f.x; l.x = (_Float16)((f.x - (float)h.x) * 2048.0f);
  h.y = (_Float16)f.y; l.y = (_Float16)((f.y - (float)h.y) * 2048.0f);
  h.z = (_Float16)f.z; l.z = (_Float16)((f.z - (float)h.z) * 2048.0f);
  h.w = (_Float16)f.w; l.w = (_Float16)((f.w - (float)h.w) * 2048.0f);
}

// One 32x64 tile of C[512,N] = A[512,K] @ W[N,K]^T + bias. A,W fp32 in global;
// f16 hi/lo split happens in-register at staging. 4 MFMA products recombined
// in fp32 epilogue (~2^-22 relative error).
__device__ __forceinline__ void mfma_tile(
    const float* __restrict__ A, int lda, int K,
    const float* __restrict__ W,
    const float* __restrict__ bias,
    float* __restrict__ Cf, float* __restrict__ Yd, int ldc,
    int act, int epi, int stage, float hs,
    const float* __restrict__ hb,
    const float* __restrict__ k0, const float* __restrict__ k1,
    const float* __restrict__ k2, const float* __restrict__ k3,
    const float* __restrict__ k4,
    int row0, int col0, _Float16* __restrict__ lds)
{
  const int tid = threadIdx.x;
  const int ln  = tid & 63;
  const int l16 = ln & 15;
  const int qd  = ln >> 4;
  const int wv  = tid >> 6;    // 0..7
  const int wr  = wv >> 2;     // 0..1 row-block (16 rows each)
  const int wc  = wv & 3;      // 0..3 col-block (16 cols each)

  // staging roles: tid<256 stage A (32x32 fp32/chunk), tid>=256 stage B (64x32)
  const int isA  = (tid < 256);
  const int arow = (tid & 255) >> 3, akq = tid & 7;   // A: 4 floats each
  const int bcol = (tid & 255) >> 2, bkq = tid & 3;   // B: 8 floats each

  const float* gA = A + (size_t)(row0 + arow) * lda + (akq << 2);
  const float* gB = W + (size_t)(col0 + bcol) * K + (bkq << 3);
  const int NC = K >> 5;

  floatx4 Phh = {0,0,0,0}, Phl = {0,0,0,0}, Plh = {0,0,0,0}, Pll = {0,0,0,0};

  float4 ra, rb0, rb1;
  if (isA) ra = *(const float4*)gA;
  else { rb0 = *(const float4*)gB; rb1 = *(const float4*)(gB + 4); }

  auto stage_store = [&](int bufsel) {
    _Float16* buf = lds + bufsel * CHUNK_HALFS;
    if (isA) {
      half4v h, l; split4(ra, h, l);
      const int ai = arow * 40 + (akq << 2);
      *(half4v*)&buf[AHI + ai] = h;
      *(half4v*)&buf[ALO + ai] = l;
    } else {
      half4v h0, l0, h1, l1; split4(rb0, h0, l0); split4(rb1, h1, l1);
      const int bi = bcol * 40 + (bkq << 3);
      *(half4v*)&buf[BHI + bi]     = h0;
      *(half4v*)&buf[BHI + bi + 4] = h1;
      *(half4v*)&buf[BLO + bi]     = l0;
      *(half4v*)&buf[BLO + bi + 4] = l1;
    }
  };

  __syncthreads();          // prior tile's readers done with buf0
  stage_store(0);

  const int aoff = AHI + ((wr << 4) + l16) * 40 + (qd << 3);
  const int boff = BHI + ((wc << 4) + l16) * 40 + (qd << 3);

  for (int c = 0; c < NC; ++c) {
    __syncthreads();        // buf[c&1] visible; buf[(c+1)&1] free
    if (c + 1 < NC) {       // prefetch next chunk (global, overlapped w/ MFMA)
      if (isA) ra = *(const float4*)(gA + ((c + 1) << 5));
      else {
        rb0 = *(const float4*)(gB + ((c + 1) << 5));
        rb1 = *(const float4*)(gB + ((c + 1) << 5) + 4);
      }
    }
    const _Float16* rbuf = lds + (c & 1) * CHUNK_HALFS;
    half8 ah = *(const half8*)&rbuf[aoff];
    half8 al = *(const half8*)&rbuf[aoff + (ALO - AHI)];
    half8 bh = *(const half8*)&rbuf[boff];
    half8 bl = *(const half8*)&rbuf[boff + (BLO - BHI)];
    Phh = MFMA16(ah, bh, Phh);
    Phl = MFMA16(ah, bl, Phl);
    Plh = MFMA16(al, bh, Plh);
    Pll = MFMA16(al, bl, Pll);
    if (c + 1 < NC) stage_store((c + 1) & 1);
  }

  // Epilogue. C/D layout: col = lane&15, row = (lane>>4)*4 + i (m89-verified)
  const int col   = col0 + (wc << 4) + l16;
  const int rbase = row0 + (wr << 4) + (qd << 2);
  const float bb = bias[col];
#pragma unroll
  for (int i = 0; i < 4; ++i) {
    float v = Phh[i] + (Phl[i] + Plh[i]) * (1.0f/2048.0f)
            + Pll[i] * (1.0f/4194304.0f) + bb;
    if (act) v = tanhf(v);
    const size_t off = (size_t)(rbase + i) * ldc + col;
    if (epi == EPI_NONE) {
      Cf[off] = v;
    } else {
      if (Cf) Cf[off] = v;             // k_stage (not stored for stage 5)
      float yv = hb[off];
      const float* DP = DPA_C[stage];
      if (stage > 0) yv = fmaf(hs * DP[0], k0[off], yv);
      if (stage > 1 && DP[1] != 0.f) yv = fmaf(hs * DP[1], k1[off], yv);
      if (stage > 2) yv = fmaf(hs * DP[2], k2[off], yv);
      if (stage > 3) yv = fmaf(hs * DP[3], k3[off], yv);
      if (stage > 4) yv = fmaf(hs * DP[4], k4[off], yv);
      yv = fmaf(hs * DP[stage], v, yv);
      Yd[off] = yv;                    // y_{stage+1} or h_next
    }
  }
}

__device__ void run_phase(
    const float* A, int lda, int K,
    const float* W, const float* bias, int N,
    float* Cf, float* Yd, int ldc,
    int act, int epi, int stage, float hs,
    const float* hb,
    const float* k0, const float* k1, const float* k2,
    const float* k3, const float* k4, _Float16* lds)
{
  const int tilesN = N >> 6;
  if (tilesN >= 16) {
    // XCD swizzle: blocks sharing a column-slice land on one XCD (L2-resident W)
    const int b = blockIdx.x;
    const int tm  = b >> 4;
    const int tn0 = ((b & 7) << 1) | ((b >> 3) & 1);
    for (int i = 0; i < (tilesN >> 4); ++i)
      mfma_tile(A, lda, K, W, bias, Cf, Yd, ldc, act, epi, stage, hs,
                hb, k0, k1, k2, k3, k4, tm << 5, (tn0 + (i << 4)) << 6, lds);
  } else {
    const int total = tilesN << 4;
    for (int t = blockIdx.x; t < total; t += GRID)
      mfma_tile(A, lda, K, W, bias, Cf, Yd, ldc, act, epi, stage, hs,
                hb, k0, k1, k2, k3, k4,
                (t / tilesN) << 5, (t % tilesN) << 6, lds);
  }
}

__global__ __launch_bounds__(BLOCK, 2) void ode_gru_kernel(KArgs a) {
  cg::grid_group grid = cg::this_grid();
  __shared__ __align__(16) _Float16 lds[2 * CHUNK_HALFS];
  const int g0 = blockIdx.x * BLOCK + threadIdx.x;
  const int gs = GRID * BLOCK;

  // ---- preamble: init barrier + h=0 (ws is re-poisoned every call) ----
  if (threadIdx.x == 0) {
    __hip_atomic_store(&a.slots[blockIdx.x], 0u, __ATOMIC_RELAXED, __HIP_MEMORY_SCOPE_AGENT);
    if (blockIdx.x == 0)
      __hip_atomic_store(a.root, 0u, __ATOMIC_RELAXED, __HIP_MEMORY_SCOPE_AGENT);
  }
  for (int i = g0; i < Bz * Hz; i += gs) a.hA[i] = 0.f;
  grid.sync();   // single cg sync covers barrier + h init

  unsigned ep = 0;
  float* h  = a.hA;
  float* hn = a.hB;

  for (int s = 0; s < Sz; ++s) {
    if (s > 0) {
      const float dt = a.t[s] - a.t[s - 1];
      const float hs = dt * (1.0f / NSUB);
      for (int sub = 0; sub < NSUB; ++sub) {
        for (int st = 0; st < 6; ++st) {
          const float* yin = (st == 0) ? h : a.y;
          // L1 (tanh)
          run_phase(yin, Hz, Hz, a.w0, a.b0, Hz, a.t1, nullptr, Hz, 1,
                    EPI_NONE, 0, 0.f, nullptr,
                    a.k0, a.k1, a.k2, a.k3, a.k4, lds);
          gbar(a.slots, a.root, ++ep);
          // L2 (tanh)
          run_phase(a.t1, Hz, Hz, a.w1, a.b1, Hz, a.t2, nullptr, Hz, 1,
                    EPI_NONE, 0, 0.f, nullptr,
                    a.k0, a.k1, a.k2, a.k3, a.k4, lds);
          gbar(a.slots, a.root, ++ep);
          // L3 (linear) + fused dopri5 combine in epilogue
          if (st < 5) {
            float* kd = (st == 0) ? a.k0 : (st == 1) ? a.k1 : (st == 2) ? a.k2
                      : (st == 3) ? a.k3 : a.k4;
            run_phase(a.t2, Hz, Hz, a.w2, a.b2, Hz, kd, a.y, Hz, 0,
                      EPI_Y, st, hs, h,
                      a.k0, a.k1, a.k2, a.k3, a.k4, lds);
          } else {  // FSAL: h_next = y_6
            run_phase(a.t2, Hz, Hz, a.w2, a.b2, Hz, nullptr, hn, Hz, 0,
                      EPI_H, 5, hs, h,
                      a.k0, a.k1, a.k2, a.k3, a.k4, lds);
          }
          gbar(a.slots, a.root, ++ep);
        }
        { float* tp = h; h = hn; hn = tp; }
      }
    }

    // GRU gates: gi = x_s@Wih^T+b ; gh = h@Whh^T+b (independent, one barrier)
    run_phase(a.x + (size_t)s * Dz, Sz * Dz, Dz, a.w_ih, a.b_ih, 3 * Hz,
              a.gi, nullptr, 3 * Hz, 0, EPI_NONE, 0, 0.f, nullptr,
              a.k0, a.k1, a.k2, a.k3, a.k4, lds);
    run_phase(h, Hz, Hz, a.w_hh, a.b_hh, 3 * Hz,
              a.gh, nullptr, 3 * Hz, 0, EPI_NONE, 0, 0.f, nullptr,
              a.k0, a.k1, a.k2, a.k3, a.k4, lds);
    gbar(a.slots, a.root, ++ep);

    // GRU pointwise
    for (int i = g0; i < Bz * Hz; i += gs) {
      const int b = i >> 10;
      const int j = i & (Hz - 1);
      const size_t g = (size_t)b * 3 * Hz + j;
      const float ir  = a.gi[g];
      const float iz  = a.gi[g + Hz];
      const float inn = a.gi[g + 2 * Hz];
      const float hr  = a.gh[g];
      const float hzv = a.gh[g + Hz];
      const float hnn = a.gh[g + 2 * Hz];
      const float rr  = 1.f / (1.f + expf(-(ir + hr)));
      const float zz  = 1.f / (1.f + expf(-(iz + hzv)));
      const float nnv = tanhf(inn + rr * hnn);
      hn[i] = (1.f - zz) * nnv + zz * h[i];
    }
    gbar(a.slots, a.root, ++ep);
    { float* tp = h; h = hn; hn = tp; }
  }

  // Final projections: mu then logvar, concatenated in d_out
  run_phase(h, Hz, Hz, a.mu_w, a.mu_b, Lz, a.out, nullptr, Lz, 0,
            EPI_NONE, 0, 0.f, nullptr, a.k0, a.k1, a.k2, a.k3, a.k4, lds);
  run_phase(h, Hz, Hz, a.lv_w, a.lv_b, Lz, a.out + (size_t)Bz * Lz, nullptr,
            Lz, 0, EPI_NONE, 0, 0.f, nullptr, a.k0, a.k1, a.k2, a.k3, a.k4, lds);
}

extern "C" void kernel_launch(void* const* d_in, const int* in_sizes, int n_in,
                              void* d_out, int out_size, void* d_ws, size_t ws_size,
                              hipStream_t stream) {
  KArgs a;
  a.x    = (const float*)d_in[0];
  a.t    = (const float*)d_in[1];
  a.w_ih = (const float*)d_in[2];
  a.w_hh = (const float*)d_in[3];
  a.b_ih = (const float*)d_in[4];
  a.b_hh = (const float*)d_in[5];
  a.w0   = (const float*)d_in[6];
  a.b0   = (const float*)d_in[7];
  a.w1   = (const float*)d_in[8];
  a.b1   = (const float*)d_in[9];
  a.w2   = (const float*)d_in[10];
  a.b2   = (const float*)d_in[11];
  a.mu_w = (const float*)d_in[12];
  a.mu_b = (const float*)d_in[13];
  a.lv_w = (const float*)d_in[14];
  a.lv_b = (const float*)d_in[15];
  a.out  = (float*)d_out;

  float* ws = (float*)d_ws;
  const size_t BH = (size_t)Bz * Hz;   // 524288 floats
  a.hA = ws + 0 * BH;
  a.hB = ws + 1 * BH;
  a.y  = ws + 2 * BH;
  a.t1 = ws + 3 * BH;
  a.t2 = ws + 4 * BH;
  a.k0 = ws + 5 * BH;
  a.k1 = ws + 6 * BH;
  a.k2 = ws + 7 * BH;
  a.k3 = ws + 8 * BH;
  a.k4 = ws + 9 * BH;
  // aliases (dead regions during GRU): gi over k0..k2, gh over y,t1,t2
  a.gi = a.k0;
  a.gh = a.y;
  // barrier block: total ws use = 20 MiB + 4 KiB (round-1 proved >= 32 MiB ok)
  a.slots = (unsigned*)(ws + 10 * BH);
  a.root  = a.slots + 320;
  (void)ws_size; (void)in_sizes; (void)n_in; (void)out_size;

  KArgs args_val = a;
  void* params[] = { &args_val };
  hipLaunchCooperativeKernel((void*)ode_gru_kernel, dim3(GRID), dim3(BLOCK),
                             params, 0, stream);
}

// Round 4
// 411836.572 us; speedup vs baseline: 1.4061x; 1.0552x over previous
//
#include <hip/hip_runtime.h>
#include <hip/hip_cooperative_groups.h>
#include <math.h>

namespace cg = cooperative_groups;

// Problem constants
#define Bz 512
#define Sz 128
#define Dz 128
#define Hz 1024
#define Lz 128
#define NSUB 4

#define GRID 256
#define BLOCK 512

typedef _Float16 half8 __attribute__((ext_vector_type(8)));
typedef float floatx4 __attribute__((ext_vector_type(4)));

#define MFMA16(a, b, c) __builtin_amdgcn_mfma_f32_16x16x32_f16(a, b, c, 0, 0, 0)

// LDS: single 48 KB chunk buffer (BK=128), frag-major layout:
// operand block (k32-chunk, group16) = 64 lanes x 8 halfs contiguous (1 KB)
// -> conflict-free b128 reads (exact MFMA lane order) and writes.
#define AHI_O 0        // A hi: 8 blocks (4 k32 x 2 rowgroups) x 512 halfs
#define ALO_D 4096     // A lo delta
#define BHI_O 8192     // B hi: 16 blocks (4 k32 x 4 colgroups)
#define BLO_D 8192     // B lo delta
#define CHUNK_HALFS 24576   // 48 KB

enum { EPI_NONE = 0, EPI_Y = 1, EPI_H = 2 };

// dopri5 tableau row i+1 (input coeffs of stage i+1). Row 5 == 5th-order b
// weights (FSAL): h_next = y_6; stage-7 f-eval is dead and skipped.
__constant__ float DPA_C[6][6] = {
  {0.2f, 0.f, 0.f, 0.f, 0.f, 0.f},
  {0.075f, 0.225f, 0.f, 0.f, 0.f, 0.f},
  {44.f/45.f, -56.f/15.f, 32.f/9.f, 0.f, 0.f, 0.f},
  {19372.f/6561.f, -25360.f/2187.f, 64448.f/6561.f, -212.f/729.f, 0.f, 0.f},
  {9017.f/3168.f, -355.f/33.f, 46732.f/5247.f, 49.f/176.f, -5103.f/18656.f, 0.f},
  {35.f/384.f, 0.f, 500.f/1113.f, 125.f/192.f, -2187.f/6784.f, 11.f/84.f},
};

struct KArgs {
  const float *x, *t, *w_ih, *w_hh, *b_ih, *b_hh;
  const float *w0, *b0, *w1, *b1, *w2, *b2, *mu_w, *mu_b, *lv_w, *lv_b;
  float* out;
  float *hA, *hB, *y, *t1, *t2, *k0, *k1, *k2, *k3, *k4, *gi, *gh;
  unsigned *slots, *root;
};

// Slot barrier: no atomic-RMW contention. Block b release-stores epoch to its
// own slot; block 0's threads poll all slots, then release the root epoch.
__device__ __forceinline__ void gbar(unsigned* slots, unsigned* root, unsigned e) {
  __syncthreads();
  if (blockIdx.x == 0) {
    const int t = threadIdx.x;
    if (t > 0 && t < GRID) {
      while (__hip_atomic_load(&slots[t], __ATOMIC_ACQUIRE, __HIP_MEMORY_SCOPE_AGENT) < e)
        __builtin_amdgcn_s_sleep(2);
    }
    __syncthreads();
    if (t == 0)
      __hip_atomic_store(root, e, __ATOMIC_RELEASE, __HIP_MEMORY_SCOPE_AGENT);
  } else {
    if (threadIdx.x == 0) {
      __hip_atomic_store(&slots[blockIdx.x], e, __ATOMIC_RELEASE, __HIP_MEMORY_SCOPE_AGENT);
      while (__hip_atomic_load(root, __ATOMIC_ACQUIRE, __HIP_MEMORY_SCOPE_AGENT) < e)
        __builtin_amdgcn_s_sleep(2);
    }
  }
  __syncthreads();
}

__device__ __forceinline__ void split8(float4 a, float4 b, half8& h, half8& l) {
  float v[8] = {a.x, a.y, a.z, a.w, b.x, b.y, b.z, b.w};
#pragma unroll
  for (int i = 0; i < 8; ++i) {
    _Float16 hh = (_Float16)v[i];
    h[i] = hh;
    l[i] = (_Float16)((v[i] - (float)hh) * 2048.0f);
  }
}

// One 32x64 tile of C[512,N] = A[512,K] @ W[N,K]^T + bias. A,W fp32 in global;
// f16 hi/lo split in-register at staging; 4 MFMA products recombined in fp32
// (~2^-22 rel error). BK=128: 8 latency windows per K=1024 with 6 loads each
// in flight a full iteration ahead of consumption.
__device__ __forceinline__ void mfma_tile(
    const float* __restrict__ A, int lda, int K,
    const float* __restrict__ W,
    const float* __restrict__ bias,
    float* __restrict__ Cf, float* __restrict__ Yd, int ldc,
    int act, int epi, int stage, float hs,
    const float* __restrict__ hb,
    const float* __restrict__ k0, const float* __restrict__ k1,
    const float* __restrict__ k2, const float* __restrict__ k3,
    const float* __restrict__ k4,
    int row0, int col0, _Float16* __restrict__ lds)
{
  const int tid = threadIdx.x;
  const int ln  = tid & 63;
  const int l16 = ln & 15;
  const int qd  = ln >> 4;
  const int wv  = tid >> 6;    // 0..7
  const int wr  = wv >> 2;     // 0..1 row-group (16 rows)
  const int wc  = wv & 3;      // 0..3 col-group (16 cols)

  // Staging: each thread owns 8-fp32 segments: 1 of A (32x128/chunk),
  // 2 of B (64x128/chunk). seg k-index shared (tid&15).
  const int an    = tid >> 4;          // A row 0..31 (also B col for seg0)
  const int seg   = tid & 15;          // k-segment (8 floats) within BK=128
  const int bcol1 = 32 + an;
  const float* gA  = A + (size_t)(row0 + an) * lda + (seg << 3);
  const float* gB0 = W + (size_t)(col0 + an) * K + (seg << 3);
  const float* gB1 = W + (size_t)(col0 + bcol1) * K + (seg << 3);
  // frag-major LDS offsets (halfs): block = (k32_chunk * NG + group16)
  const int c_ = seg >> 2, q_ = seg & 3;
  const int aoff  = AHI_O + ((c_ * 2 + (an >> 4)) * 64 + q_ * 16 + (an & 15)) * 8;
  const int boff0 = BHI_O + ((c_ * 4 + (an >> 4)) * 64 + q_ * 16 + (an & 15)) * 8;
  const int boff1 = BHI_O + ((c_ * 4 + (bcol1 >> 4)) * 64 + q_ * 16 + (bcol1 & 15)) * 8;

  const int NC = K >> 7;

  floatx4 Phh = {0,0,0,0}, Phl = {0,0,0,0}, Plh = {0,0,0,0}, Pll = {0,0,0,0};

  float4 ra0, ra1, rb00, rb01, rb10, rb11;
  auto load6 = [&](int kk) {
    ra0  = *(const float4*)(gA + kk);
    ra1  = *(const float4*)(gA + kk + 4);
    rb00 = *(const float4*)(gB0 + kk);
    rb01 = *(const float4*)(gB0 + kk + 4);
    rb10 = *(const float4*)(gB1 + kk);
    rb11 = *(const float4*)(gB1 + kk + 4);
  };
  auto store6 = [&]() {
    half8 h, l;
    split8(ra0, ra1, h, l);
    *(half8*)&lds[aoff] = h;
    *(half8*)&lds[aoff + ALO_D] = l;
    split8(rb00, rb01, h, l);
    *(half8*)&lds[boff0] = h;
    *(half8*)&lds[boff0 + BLO_D] = l;
    split8(rb10, rb11, h, l);
    *(half8*)&lds[boff1] = h;
    *(half8*)&lds[boff1 + BLO_D] = l;
  };

  load6(0);
  __syncthreads();               // prior tile's readers done with the buffer
  store6();
  if (NC > 1) load6(128);

  for (int c = 0; c < NC; ++c) {
    __syncthreads();             // chunk c stores visible
#pragma unroll
    for (int kq = 0; kq < 4; ++kq) {
      const int ab = ((kq * 2 + wr) * 64 + ln) * 8;
      const int bb = BHI_O + ((kq * 4 + wc) * 64 + ln) * 8;
      half8 ah = *(const half8*)&lds[ab];
      half8 al = *(const half8*)&lds[ab + ALO_D];
      half8 bh = *(const half8*)&lds[bb];
      half8 bl = *(const half8*)&lds[bb + BLO_D];
      Phh = MFMA16(ah, bh, Phh);
      Phl = MFMA16(ah, bl, Phl);
      Plh = MFMA16(al, bh, Plh);
      Pll = MFMA16(al, bl, Pll);
    }
    __syncthreads();             // all reads of chunk c done
    if (c + 1 < NC) {
      store6();                  // regs (loaded a full iteration ago) -> LDS
      if (c + 2 < NC) load6((c + 2) << 7);
    }
  }

  // Epilogue. C/D layout: col = lane&15, row = (lane>>4)*4 + i (m89-verified)
  const int col   = col0 + (wc << 4) + l16;
  const int rbase = row0 + (wr << 4) + (qd << 2);
  const float bb = bias[col];
#pragma unroll
  for (int i = 0; i < 4; ++i) {
    float v = Phh[i] + (Phl[i] + Plh[i]) * (1.0f/2048.0f)
            + Pll[i] * (1.0f/4194304.0f) + bb;
    if (act) v = tanhf(v);
    const size_t off = (size_t)(rbase + i) * ldc + col;
    if (epi == EPI_NONE) {
      Cf[off] = v;
    } else {
      if (Cf) Cf[off] = v;             // k_stage (not stored for stage 5)
      float yv = hb[off];
      const float* DP = DPA_C[stage];
      if (stage > 0) yv = fmaf(hs * DP[0], k0[off], yv);
      if (stage > 1 && DP[1] != 0.f) yv = fmaf(hs * DP[1], k1[off], yv);
      if (stage > 2) yv = fmaf(hs * DP[2], k2[off], yv);
      if (stage > 3) yv = fmaf(hs * DP[3], k3[off], yv);
      if (stage > 4) yv = fmaf(hs * DP[4], k4[off], yv);
      yv = fmaf(hs * DP[stage], v, yv);
      Yd[off] = yv;                    // y_{stage+1} or h_next
    }
  }
}

__device__ void run_phase(
    const float* A, int lda, int K,
    const float* W, const float* bias, int N,
    float* Cf, float* Yd, int ldc,
    int act, int epi, int stage, float hs,
    const float* hb,
    const float* k0, const float* k1, const float* k2,
    const float* k3, const float* k4, _Float16* lds)
{
  const int tilesN = N >> 6;
  if (tilesN >= 16) {
    // XCD swizzle: blocks sharing a column-slice land on one XCD (L2-resident W)
    const int b = blockIdx.x;
    const int tm  = b >> 4;
    const int tn0 = ((b & 7) << 1) | ((b >> 3) & 1);
    for (int i = 0; i < (tilesN >> 4); ++i)
      mfma_tile(A, lda, K, W, bias, Cf, Yd, ldc, act, epi, stage, hs,
                hb, k0, k1, k2, k3, k4, tm << 5, (tn0 + (i << 4)) << 6, lds);
  } else {
    const int total = tilesN << 4;
    for (int t = blockIdx.x; t < total; t += GRID)
      mfma_tile(A, lda, K, W, bias, Cf, Yd, ldc, act, epi, stage, hs,
                hb, k0, k1, k2, k3, k4,
                (t / tilesN) << 5, (t % tilesN) << 6, lds);
  }
}

__global__ __launch_bounds__(BLOCK, 2) void ode_gru_kernel(KArgs a) {
  cg::grid_group grid = cg::this_grid();
  __shared__ __align__(16) _Float16 lds[CHUNK_HALFS];   // 48 KB
  const int g0 = blockIdx.x * BLOCK + threadIdx.x;
  const int gs = GRID * BLOCK;

  // ---- preamble: init barrier + h=0 (ws is re-poisoned every call) ----
  if (threadIdx.x == 0) {
    __hip_atomic_store(&a.slots[blockIdx.x], 0u, __ATOMIC_RELAXED, __HIP_MEMORY_SCOPE_AGENT);
    if (blockIdx.x == 0)
      __hip_atomic_store(a.root, 0u, __ATOMIC_RELAXED, __HIP_MEMORY_SCOPE_AGENT);
  }
  for (int i = g0; i < Bz * Hz; i += gs) a.hA[i] = 0.f;
  grid.sync();   // single cg sync covers barrier + h init

  unsigned ep = 0;
  float* h  = a.hA;
  float* hn = a.hB;

  for (int s = 0; s < Sz; ++s) {
    if (s > 0) {
      const float dt = a.t[s] - a.t[s - 1];
      const float hs = dt * (1.0f / NSUB);
      for (int sub = 0; sub < NSUB; ++sub) {
        for (int st = 0; st < 6; ++st) {
          const float* yin = (st == 0) ? h : a.y;
          // L1 (tanh)
          run_phase(yin, Hz, Hz, a.w0, a.b0, Hz, a.t1, nullptr, Hz, 1,
                    EPI_NONE, 0, 0.f, nullptr,
                    a.k0, a.k1, a.k2, a.k3, a.k4, lds);
          gbar(a.slots, a.root, ++ep);
          // L2 (tanh)
          run_phase(a.t1, Hz, Hz, a.w1, a.b1, Hz, a.t2, nullptr, Hz, 1,
                    EPI_NONE, 0, 0.f, nullptr,
                    a.k0, a.k1, a.k2, a.k3, a.k4, lds);
          gbar(a.slots, a.root, ++ep);
          // L3 (linear) + fused dopri5 combine in epilogue
          if (st < 5) {
            float* kd = (st == 0) ? a.k0 : (st == 1) ? a.k1 : (st == 2) ? a.k2
                      : (st == 3) ? a.k3 : a.k4;
            run_phase(a.t2, Hz, Hz, a.w2, a.b2, Hz, kd, a.y, Hz, 0,
                      EPI_Y, st, hs, h,
                      a.k0, a.k1, a.k2, a.k3, a.k4, lds);
          } else {  // FSAL: h_next = y_6
            run_phase(a.t2, Hz, Hz, a.w2, a.b2, Hz, nullptr, hn, Hz, 0,
                      EPI_H, 5, hs, h,
                      a.k0, a.k1, a.k2, a.k3, a.k4, lds);
          }
          gbar(a.slots, a.root, ++ep);
        }
        { float* tp = h; h = hn; hn = tp; }
      }
    }

    // GRU gates: gi = x_s@Wih^T+b ; gh = h@Whh^T+b (independent, one barrier)
    run_phase(a.x + (size_t)s * Dz, Sz * Dz, Dz, a.w_ih, a.b_ih, 3 * Hz,
              a.gi, nullptr, 3 * Hz, 0, EPI_NONE, 0, 0.f, nullptr,
              a.k0, a.k1, a.k2, a.k3, a.k4, lds);
    run_phase(h, Hz, Hz, a.w_hh, a.b_hh, 3 * Hz,
              a.gh, nullptr, 3 * Hz, 0, EPI_NONE, 0, 0.f, nullptr,
              a.k0, a.k1, a.k2, a.k3, a.k4, lds);
    gbar(a.slots, a.root, ++ep);

    // GRU pointwise
    for (int i = g0; i < Bz * Hz; i += gs) {
      const int b = i >> 10;
      const int j = i & (Hz - 1);
      const size_t g = (size_t)b * 3 * Hz + j;
      const float ir  = a.gi[g];
      const float iz  = a.gi[g + Hz];
      const float inn = a.gi[g + 2 * Hz];
      const float hr  = a.gh[g];
      const float hzv = a.gh[g + Hz];
      const float hnn = a.gh[g + 2 * Hz];
      const float rr  = 1.f / (1.f + expf(-(ir + hr)));
      const float zz  = 1.f / (1.f + expf(-(iz + hzv)));
      const float nnv = tanhf(inn + rr * hnn);
      hn[i] = (1.f - zz) * nnv + zz * h[i];
    }
    gbar(a.slots, a.root, ++ep);
    { float* tp = h; h = hn; hn = tp; }
  }

  // Final projections: mu then logvar, concatenated in d_out
  run_phase(h, Hz, Hz, a.mu_w, a.mu_b, Lz, a.out, nullptr, Lz, 0,
            EPI_NONE, 0, 0.f, nullptr, a.k0, a.k1, a.k2, a.k3, a.k4, lds);
  run_phase(h, Hz, Hz, a.lv_w, a.lv_b, Lz, a.out + (size_t)Bz * Lz, nullptr,
            Lz, 0, EPI_NONE, 0, 0.f, nullptr, a.k0, a.k1, a.k2, a.k3, a.k4, lds);
}

extern "C" void kernel_launch(void* const* d_in, const int* in_sizes, int n_in,
                              void* d_out, int out_size, void* d_ws, size_t ws_size,
                              hipStream_t stream) {
  KArgs a;
  a.x    = (const float*)d_in[0];
  a.t    = (const float*)d_in[1];
  a.w_ih = (const float*)d_in[2];
  a.w_hh = (const float*)d_in[3];
  a.b_ih = (const float*)d_in[4];
  a.b_hh = (const float*)d_in[5];
  a.w0   = (const float*)d_in[6];
  a.b0   = (const float*)d_in[7];
  a.w1   = (const float*)d_in[8];
  a.b1   = (const float*)d_in[9];
  a.w2   = (const float*)d_in[10];
  a.b2   = (const float*)d_in[11];
  a.mu_w = (const float*)d_in[12];
  a.mu_b = (const float*)d_in[13];
  a.lv_w = (const float*)d_in[14];
  a.lv_b = (const float*)d_in[15];
  a.out  = (float*)d_out;

  float* ws = (float*)d_ws;
  const size_t BH = (size_t)Bz * Hz;   // 524288 floats
  a.hA = ws + 0 * BH;
  a.hB = ws + 1 * BH;
  a.y  = ws + 2 * BH;
  a.t1 = ws + 3 * BH;
  a.t2 = ws + 4 * BH;
  a.k0 = ws + 5 * BH;
  a.k1 = ws + 6 * BH;
  a.k2 = ws + 7 * BH;
  a.k3 = ws + 8 * BH;
  a.k4 = ws + 9 * BH;
  // aliases (dead regions during GRU): gi over k0..k2, gh over y,t1,t2
  a.gi = a.k0;
  a.gh = a.y;
  // barrier block: total ws use = 20 MiB + 4 KiB (proven safe in R1/R3)
  a.slots = (unsigned*)(ws + 10 * BH);
  a.root  = a.slots + 320;
  (void)ws_size; (void)in_sizes; (void)n_in; (void)out_size;

  KArgs args_val = a;
  void* params[] = { &args_val };
  hipLaunchCooperativeKernel((void*)ode_gru_kernel, dim3(GRID), dim3(BLOCK),
                             params, 0, stream);
}

// Round 5
// 156684.851 us; speedup vs baseline: 3.6958x; 2.6284x over previous
//
#include <hip/hip_runtime.h>
#include <math.h>

// Problem constants
#define Bz 512
#define Sz 128
#define Dz 128
#define Hz 1024
#define Lz 128
#define NSUB 4

#define GRID 256
#define BLOCK 512
#define NGRP 16   // independent groups (32 batch rows each)
#define GBLK 16   // blocks per group

typedef _Float16 half8 __attribute__((ext_vector_type(8)));
typedef float floatx4 __attribute__((ext_vector_type(4)));
typedef unsigned long long u64;

#define MFMA16(a, b, c) __builtin_amdgcn_mfma_f32_16x16x32_f16(a, b, c, 0, 0, 0)

// LDS frag-major layout (halfs), BK=128, one 48 KB buffer.
// unit = 16B lane-chunk; XOR swizzle on unit low bits spreads writes
// over all 8 bank-groups (R4's layout used only banks 0-15 on writes).
#define AHI_O 0
#define ALO_D 4096
#define BHI_O 8192
#define BLO_D 8192
#define CHUNK_HALFS 24576

enum { EPI_NONE = 0, EPI_Y = 1, EPI_H = 2 };

// dopri5 tableau row i+1 (input coeffs of stage i+1). Row 5 == 5th-order b
// weights (FSAL): h_next = y_6; stage-7 f-eval is dead and skipped.
__constant__ float DPA_C[6][6] = {
  {0.2f, 0.f, 0.f, 0.f, 0.f, 0.f},
  {0.075f, 0.225f, 0.f, 0.f, 0.f, 0.f},
  {44.f/45.f, -56.f/15.f, 32.f/9.f, 0.f, 0.f, 0.f},
  {19372.f/6561.f, -25360.f/2187.f, 64448.f/6561.f, -212.f/729.f, 0.f, 0.f},
  {9017.f/3168.f, -355.f/33.f, 46732.f/5247.f, 49.f/176.f, -5103.f/18656.f, 0.f},
  {35.f/384.f, 0.f, 500.f/1113.f, 125.f/192.f, -2187.f/6784.f, 11.f/84.f},
};

struct KArgs {
  const float *x, *t, *w_ih, *w_hh, *b_ih, *b_hh;
  const float *w0, *b0, *w1, *b1, *w2, *b2, *mu_w, *mu_b, *lv_w, *lv_b;
  float* out;
  float *h, *y, *t1, *t2, *gi, *gh;
  unsigned* bar;   // NGRP * 64 u32: slots[0..15], root at +32
};

// ---- IF$-level (cross-XCD coherent) accesses: relaxed agent atomics set
// sc0+sc1 (bypass L1+L2) with NO cache-wiping fences. Weights stay in L2.
__device__ __forceinline__ float2 ldc2(const float* p) {
  u64 v = __hip_atomic_load((u64*)p, __ATOMIC_RELAXED, __HIP_MEMORY_SCOPE_AGENT);
  union { u64 u; float2 f; } c; c.u = v; return c.f;
}
__device__ __forceinline__ float ldc1(const float* p) {
  unsigned v = __hip_atomic_load((unsigned*)p, __ATOMIC_RELAXED, __HIP_MEMORY_SCOPE_AGENT);
  union { unsigned u; float f; } c; c.u = v; return c.f;
}
__device__ __forceinline__ void stc1(float* p, float f) {
  union { float f; unsigned u; } c; c.f = f;
  __hip_atomic_store((unsigned*)p, c.u, __ATOMIC_RELEASE == 99 ? c.u : c.u,
                     __HIP_MEMORY_SCOPE_AGENT);
}

// Group barrier (16 blocks): equality-poll (poison-safe, no slot init needed).
// Data ordering: each wave drains its IF$ stores (vmcnt) before signaling;
// flags are relaxed agent atomics -> no L2 writeback/invalidate anywhere.
__device__ __forceinline__ void gbar(unsigned* gb, int jj, unsigned e) {
  asm volatile("s_waitcnt vmcnt(0) lgkmcnt(0)" ::: "memory");
  __syncthreads();
  const int t = threadIdx.x;
  if (jj == 0) {
    if (t >= 1 && t < GBLK) {
      while (__hip_atomic_load(&gb[t], __ATOMIC_RELAXED, __HIP_MEMORY_SCOPE_AGENT) != e)
        __builtin_amdgcn_s_sleep(1);
    }
    __syncthreads();
    if (t == 0)
      __hip_atomic_store(&gb[32], e, __ATOMIC_RELAXED, __HIP_MEMORY_SCOPE_AGENT);
  } else {
    if (t == 0) {
      __hip_atomic_store(&gb[jj], e, __ATOMIC_RELAXED, __HIP_MEMORY_SCOPE_AGENT);
      while (__hip_atomic_load(&gb[32], __ATOMIC_RELAXED, __HIP_MEMORY_SCOPE_AGENT) != e)
        __builtin_amdgcn_s_sleep(1);
    }
    __syncthreads();
  }
}

__device__ __forceinline__ void split8(float4 a, float4 b, half8& h, half8& l) {
  float v[8] = {a.x, a.y, a.z, a.w, b.x, b.y, b.z, b.w};
#pragma unroll
  for (int i = 0; i < 8; ++i) {
    _Float16 hh = (_Float16)v[i];
    h[i] = hh;
    l[i] = (_Float16)((v[i] - (float)hh) * 2048.0f);
  }
}

// One 32x64 tile of C[512,N] = A[512,K] @ W[N,K]^T + bias.
// A,W fp32; f16 hi/lo split at staging; 4 MFMA products -> ~2^-22 rel error.
// ACo: A rows are cross-block activations (IF$ loads). W always plain (L2).
// k0..k4 + h-tile live in caller registers across a substep (tile mapping is
// call-invariant), so dopri5 combines need no global k traffic.
template<bool ACo>
__device__ __forceinline__ void mfma_tile(
    const float* __restrict__ A, int lda, int K,
    const float* __restrict__ W, const float* __restrict__ bias,
    float* __restrict__ Cf, float* __restrict__ Yd, int ldc,
    int act, int epi, int stage, float hs,
    const float* __restrict__ hbuf,
    floatx4& K0, floatx4& K1, floatx4& K2, floatx4& K3, floatx4& K4,
    floatx4& Hc,
    int row0, int col0, _Float16* __restrict__ lds)
{
  const int tid = threadIdx.x;
  const int ln  = tid & 63;
  const int l16 = ln & 15;
  const int qd  = ln >> 4;
  const int wv  = tid >> 6;
  const int wr  = wv >> 2;     // 0..1 row-group
  const int wc  = wv & 3;      // 0..3 col-group

  // staging: thread owns 8-fp32 k-segments: 1 A row-seg + 2 W col-segs
  const int an   = tid >> 4;         // 0..31
  const int an15 = an & 15, ang = an >> 4;
  const int seg  = tid & 15;
  const int c_ = seg >> 2, q_ = seg & 3;
  const int ua = q_ * 16 + (an15 ^ (((q_ ^ c_) & 1) << 2));   // bank swizzle
  const int aoff  = AHI_O + (((c_ * 2 + ang) * 64 + ua) << 3);
  const int boff0 = BHI_O + (((c_ * 4 + ang) * 64 + ua) << 3);
  const int boff1 = BHI_O + (((c_ * 4 + 2 + ang) * 64 + ua) << 3);

  const float* gA  = A + (size_t)(row0 + an) * lda + (seg << 3);
  const float* gB0 = W + (size_t)(col0 + an) * K + (seg << 3);
  const float* gB1 = W + (size_t)(col0 + 32 + an) * K + (seg << 3);
  const int NC = K >> 7;

  floatx4 Phh = {0,0,0,0}, Phl = {0,0,0,0}, Plh = {0,0,0,0}, Pll = {0,0,0,0};

  float4 ra0, ra1, rb00, rb01, rb10, rb11;
  auto load6 = [&](int kk) {
    if (ACo) {
      float2 a0 = ldc2(gA + kk),     a1 = ldc2(gA + kk + 2);
      float2 a2 = ldc2(gA + kk + 4), a3 = ldc2(gA + kk + 6);
      ra0 = make_float4(a0.x, a0.y, a1.x, a1.y);
      ra1 = make_float4(a2.x, a2.y, a3.x, a3.y);
    } else {
      ra0 = *(const float4*)(gA + kk);
      ra1 = *(const float4*)(gA + kk + 4);
    }
    rb00 = *(const float4*)(gB0 + kk); rb01 = *(const float4*)(gB0 + kk + 4);
    rb10 = *(const float4*)(gB1 + kk); rb11 = *(const float4*)(gB1 + kk + 4);
  };
  auto store6 = [&]() {
    half8 h, l;
    split8(ra0, ra1, h, l);
    *(half8*)&lds[aoff] = h;  *(half8*)&lds[aoff + ALO_D] = l;
    split8(rb00, rb01, h, l);
    *(half8*)&lds[boff0] = h; *(half8*)&lds[boff0 + BLO_D] = l;
    split8(rb10, rb11, h, l);
    *(half8*)&lds[boff1] = h; *(half8*)&lds[boff1 + BLO_D] = l;
  };

  load6(0);
  __syncthreads();             // prior tile's readers done with buffer
  store6();
  if (NC > 1) load6(128);

  for (int c = 0; c < NC; ++c) {
    __syncthreads();           // chunk c visible
#pragma unroll
    for (int kq = 0; kq < 4; ++kq) {
      const int lnw = ln ^ (((qd ^ kq) & 1) << 2);     // same swizzle as writer
      const int ab = ((kq * 2 + wr) * 64 + lnw) << 3;
      const int bb = BHI_O + (((kq * 4 + wc) * 64 + lnw) << 3);
      half8 ah = *(const half8*)&lds[ab];
      half8 al = *(const half8*)&lds[ab + ALO_D];
      half8 bh = *(const half8*)&lds[bb];
      half8 bl = *(const half8*)&lds[bb + BLO_D];
      Phh = MFMA16(ah, bh, Phh);
      Phl = MFMA16(ah, bl, Phl);
      Plh = MFMA16(al, bh, Plh);
      Pll = MFMA16(al, bl, Pll);
    }
    __syncthreads();           // reads of chunk c done
    if (c + 1 < NC) {
      store6();
      if (c + 2 < NC) load6((c + 2) << 7);
    }
  }

  // Epilogue. C/D layout: col = lane&15, row = (lane>>4)*4 + i (m89-verified)
  const int col   = col0 + (wc << 4) + l16;
  const int rbase = row0 + (wr << 4) + (qd << 2);
  const float bb = bias[col];
#pragma unroll
  for (int i = 0; i < 4; ++i) {
    float v = Phh[i] + (Phl[i] + Plh[i]) * (1.0f/2048.0f)
            + Pll[i] * (1.0f/4194304.0f) + bb;
    if (act) v = tanhf(v);
    const size_t off = (size_t)(rbase + i) * ldc + col;
    if (epi == EPI_NONE) {
      stc1(&Cf[off], v);
    } else {
      if (stage == 0) Hc[i] = ldc1(&hbuf[off]);   // fresh h once per substep
      float yv = Hc[i];
      const float* DP = DPA_C[stage];
      if (stage > 0) yv = fmaf(hs * DP[0], K0[i], yv);
      if (stage > 1) { float c1 = DP[1]; if (c1 != 0.f) yv = fmaf(hs * c1, K1[i], yv); }
      if (stage > 2) yv = fmaf(hs * DP[2], K2[i], yv);
      if (stage > 3) yv = fmaf(hs * DP[3], K3[i], yv);
      if (stage > 4) yv = fmaf(hs * DP[4], K4[i], yv);
      yv = fmaf(hs * DP[stage], v, yv);
      if      (stage == 0) K0[i] = v;
      else if (stage == 1) K1[i] = v;
      else if (stage == 2) K2[i] = v;
      else if (stage == 3) K3[i] = v;
      else if (stage == 4) K4[i] = v;
      stc1(&Yd[off], yv);      // y_{stage+1}, or h in place (FSAL, stage 5)
    }
  }
}

template<bool ACo>
__device__ __forceinline__ void run_phase(
    const float* A, int lda, int K,
    const float* W, const float* bias, int N,
    float* Cf, float* Yd, int ldc, int act, int epi, int stage, float hs,
    const float* hbuf,
    floatx4& K0, floatx4& K1, floatx4& K2, floatx4& K3, floatx4& K4,
    floatx4& Hc, int g, int jj, _Float16* lds)
{
  const int tilesN = N >> 6;
  const int row0 = g << 5;     // group owns rows [g*32, g*32+32)
  if (tilesN >= GBLK) {
    const int tn0 = ((jj & 7) << 1) | (jj >> 3);
    for (int i = 0; i < (tilesN >> 4); ++i)
      mfma_tile<ACo>(A, lda, K, W, bias, Cf, Yd, ldc, act, epi, stage, hs,
                     hbuf, K0, K1, K2, K3, K4, Hc,
                     row0, (tn0 + (i << 4)) << 6, lds);
  } else {
    if (jj < tilesN)
      mfma_tile<ACo>(A, lda, K, W, bias, Cf, Yd, ldc, act, epi, stage, hs,
                     hbuf, K0, K1, K2, K3, K4, Hc, row0, jj << 6, lds);
  }
}

__global__ __launch_bounds__(BLOCK, 2) void ode_gru_kernel(KArgs a) {
  __shared__ __align__(16) _Float16 lds[CHUNK_HALFS];
  const int g  = blockIdx.x >> 4;
  const int jj = blockIdx.x & 15;
  unsigned* gb = a.bar + (g << 6);
  unsigned ep = 0;

  // zero this group's h rows via IF$ stores (ws poisoned every call)
  for (int i = jj * BLOCK + threadIdx.x; i < 32 * Hz; i += GBLK * BLOCK)
    stc1(a.h + (size_t)g * 32 * Hz + i, 0.f);
  gbar(gb, jj, ++ep);

  floatx4 K0 = {0,0,0,0}, K1 = {0,0,0,0}, K2 = {0,0,0,0};
  floatx4 K3 = {0,0,0,0}, K4 = {0,0,0,0}, Hc = {0,0,0,0};

  for (int s = 0; s < Sz; ++s) {
    if (s > 0) {
      const float dt = a.t[s] - a.t[s - 1];
      const float hs = dt * (1.0f / NSUB);
      for (int sub = 0; sub < NSUB; ++sub) {
        for (int st = 0; st < 6; ++st) {
          const float* yin = (st == 0) ? a.h : a.y;
          // L1 (tanh)
          run_phase<true>(yin, Hz, Hz, a.w0, a.b0, Hz, a.t1, nullptr, Hz,
                          1, EPI_NONE, 0, 0.f, nullptr,
                          K0, K1, K2, K3, K4, Hc, g, jj, lds);
          gbar(gb, jj, ++ep);
          // L2 (tanh)
          run_phase<true>(a.t1, Hz, Hz, a.w1, a.b1, Hz, a.t2, nullptr, Hz,
                          1, EPI_NONE, 0, 0.f, nullptr,
                          K0, K1, K2, K3, K4, Hc, g, jj, lds);
          gbar(gb, jj, ++ep);
          // L3 (linear) + fused dopri5 combine; k's stay in registers
          if (st < 5) {
            run_phase<true>(a.t2, Hz, Hz, a.w2, a.b2, Hz, nullptr, a.y, Hz,
                            0, EPI_Y, st, hs, a.h,
                            K0, K1, K2, K3, K4, Hc, g, jj, lds);
          } else {   // FSAL: h_next = y_6, written to h in place
            run_phase<true>(a.t2, Hz, Hz, a.w2, a.b2, Hz, nullptr, a.h, Hz,
                            0, EPI_H, 5, hs, a.h,
                            K0, K1, K2, K3, K4, Hc, g, jj, lds);
          }
          gbar(gb, jj, ++ep);
        }
      }
    }

    // GRU gates: gi = x_s@Wih^T+b ; gh = h@Whh^T+b (independent, one barrier)
    run_phase<false>(a.x + (size_t)s * Dz, Sz * Dz, Dz, a.w_ih, a.b_ih, 3 * Hz,
                     a.gi, nullptr, 3 * Hz, 0, EPI_NONE, 0, 0.f, nullptr,
                     K0, K1, K2, K3, K4, Hc, g, jj, lds);
    run_phase<true>(a.h, Hz, Hz, a.w_hh, a.b_hh, 3 * Hz,
                    a.gh, nullptr, 3 * Hz, 0, EPI_NONE, 0, 0.f, nullptr,
                    K0, K1, K2, K3, K4, Hc, g, jj, lds);
    gbar(gb, jj, ++ep);

    // GRU pointwise, h updated in place (group-local rows)
    for (int i = jj * BLOCK + threadIdx.x; i < 32 * Hz; i += GBLK * BLOCK) {
      const int r = g * 32 + (i >> 10);
      const int c = i & (Hz - 1);
      const size_t gx = (size_t)r * 3 * Hz + c;
      const size_t hx = (size_t)r * Hz + c;
      const float ir  = ldc1(a.gi + gx);
      const float iz  = ldc1(a.gi + gx + Hz);
      const float inn = ldc1(a.gi + gx + 2 * Hz);
      const float hr  = ldc1(a.gh + gx);
      const float hzv = ldc1(a.gh + gx + Hz);
      const float hnn = ldc1(a.gh + gx + 2 * Hz);
      const float hv  = ldc1(a.h + hx);
      const float rr  = 1.f / (1.f + expf(-(ir + hr)));
      const float zz  = 1.f / (1.f + expf(-(iz + hzv)));
      const float nnv = tanhf(inn + rr * hnn);
      stc1(a.h + hx, (1.f - zz) * nnv + zz * hv);
    }
    gbar(gb, jj, ++ep);
  }

  // Final projections (row-local; blocks jj<2 of each group do 1 tile each)
  run_phase<true>(a.h, Hz, Hz, a.mu_w, a.mu_b, Lz, a.out, nullptr, Lz,
                  0, EPI_NONE, 0, 0.f, nullptr,
                  K0, K1, K2, K3, K4, Hc, g, jj, lds);
  run_phase<true>(a.h, Hz, Hz, a.lv_w, a.lv_b, Lz, a.out + (size_t)Bz * Lz,
                  nullptr, Lz, 0, EPI_NONE, 0, 0.f, nullptr,
                  K0, K1, K2, K3, K4, Hc, g, jj, lds);
}

extern "C" void kernel_launch(void* const* d_in, const int* in_sizes, int n_in,
                              void* d_out, int out_size, void* d_ws, size_t ws_size,
                              hipStream_t stream) {
  KArgs a;
  a.x    = (const float*)d_in[0];
  a.t    = (const float*)d_in[1];
  a.w_ih = (const float*)d_in[2];
  a.w_hh = (const float*)d_in[3];
  a.b_ih = (const float*)d_in[4];
  a.b_hh = (const float*)d_in[5];
  a.w0   = (const float*)d_in[6];
  a.b0   = (const float*)d_in[7];
  a.w1   = (const float*)d_in[8];
  a.b1   = (const float*)d_in[9];
  a.w2   = (const float*)d_in[10];
  a.b2   = (const float*)d_in[11];
  a.mu_w = (const float*)d_in[12];
  a.mu_b = (const float*)d_in[13];
  a.lv_w = (const float*)d_in[14];
  a.lv_b = (const float*)d_in[15];
  a.out  = (float*)d_out;

  float* ws = (float*)d_ws;
  const size_t BH = (size_t)Bz * Hz;   // 524288 floats
  a.h  = ws + 0 * BH;
  a.y  = ws + 1 * BH;
  a.t1 = ws + 2 * BH;
  a.t2 = ws + 3 * BH;
  a.gi = ws + 4 * BH;            // [512, 3072] = 3*BH
  a.gh = ws + 7 * BH;            // [512, 3072] = 3*BH
  a.bar = (unsigned*)(ws + 10 * BH);   // 1024 u32; total ~20 MiB + 4 KiB
  (void)ws_size; (void)in_sizes; (void)n_in; (void)out_size;

  KArgs args_val = a;
  void* params[] = { &args_val };
  hipLaunchCooperativeKernel((void*)ode_gru_kernel, dim3(GRID), dim3(BLOCK),
                             params, 0, stream);
}